// Round 4
// baseline (996.832 us; speedup 1.0000x reference)
//
#include <hip/hip_runtime.h>
#include <hip/hip_bf16.h>
#include <math.h>

// Problem constants (B,C,D,H,W) = (2,64,32,64,96), qk=32
constexpr int Dd = 32, Hh = 64, Ww = 96;
constexpr int CSTRIDE = Dd * Hh * Ww;   // 196608
constexpr int BDIM = 384;               // 6 waves; one 16-row i-tile per wave

// ln(10000)/32 and ln(10000)/64
#define FREQ_QK 0.28782313662425574f
#define FREQ_V  0.14391156831212787f

typedef __bf16 bf16_t;
typedef bf16_t bf16x4 __attribute__((ext_vector_type(4)));
typedef bf16_t bf16x8 __attribute__((ext_vector_type(8)));
typedef float  floatx4 __attribute__((ext_vector_type(4)));

// LDS: Xs [96 w][64 c] bf16, XOR-swizzled 16B chunks (chunk' = chunk ^ (w&7)):
//   conflict-free b128 frag reads AND 2-way (free) staged b128 writes.
// Ps: 6 per-wave [16 i][100 j] bf16 slices (P transpose for PV; lgkm-only, no barrier).
// Total 31488 B -> 5 blocks/CU (157 KB LDS, 30 waves = 94% occupancy).
constexpr int OFF_PS = 96 * 64;                   // 6144 el
constexpr int PS_STRIDE = 100;
constexpr int PS_WAVE = 16 * PS_STRIDE;           // 1600 el
constexpr int SMEM_ELEMS = OFF_PS + 6 * PS_WAVE;  // 15744 el = 31488 B

static __device__ __forceinline__ floatx4 mfma32(bf16x8 a, bf16x8 b, floatx4 c) {
    return __builtin_amdgcn_mfma_f32_16x16x32_bf16(a, b, c, 0, 0, 0);
}

// zero-pad a 4-element (k=16) fragment into the k=32 slot layout:
// value for true k = quad*4+j goes to slot quad*8+j; slots quad*8+4.. are 0.
// With BOTH A and B padded this way, the 16x16x32 MFMA computes the exact
// k=16 contraction (each slot pairs the same true k; empty slots are 0*0).
static __device__ __forceinline__ bf16x8 pad_hi(bf16x4 v) {
    bf16x8 f;
    bf16_t z = (bf16_t)0.0f;
    f[0] = v[0]; f[1] = v[1]; f[2] = v[2]; f[3] = v[3];
    f[4] = z; f[5] = z; f[6] = z; f[7] = z;
    return f;
}

// weight fragment: lane row `row`, 8 consecutive c at `cbase` (A-operand for
// proj when W is the m-side; also B-operand as W^T when W is the n-side).
static __device__ __forceinline__ bf16x8 ldw(const float* W, int row, int cbase) {
    const float* p = W + row * 64 + cbase;
    float4 lo = *(const float4*)p;
    float4 hi = *(const float4*)(p + 4);
    bf16x8 f;
    f[0] = (bf16_t)lo.x; f[1] = (bf16_t)lo.y; f[2] = (bf16_t)lo.z; f[3] = (bf16_t)lo.w;
    f[4] = (bf16_t)hi.x; f[5] = (bf16_t)hi.y; f[6] = (bf16_t)hi.z; f[7] = (bf16_t)hi.w;
    return f;
}

__global__ __launch_bounds__(BDIM, 8)
void row_attn_v4(const float* __restrict__ x,
                 const float* __restrict__ Wq, const float* __restrict__ bq,
                 const float* __restrict__ Wk, const float* __restrict__ bk,
                 const float* __restrict__ Wv, const float* __restrict__ bv,
                 const float* __restrict__ gamma,
                 float* __restrict__ y)
{
    __shared__ __align__(16) bf16_t smem[SMEM_ELEMS];
    bf16_t* Xs = smem;

    const int t    = threadIdx.x;
    const int lane = t & 63;
    const int wid  = t >> 6;       // wave id 0..5 == its i-tile
    const int l16  = lane & 15;
    const int quad = lane >> 4;
    bf16_t* Psw = smem + OFF_PS + wid * PS_WAVE;

    const int bid = blockIdx.x;
    const int b   = bid / (Dd * Hh);
    const int rem = bid % (Dd * Hh);
    const int d   = rem / Hh;
    const int h   = rem % Hh;
    const int base0 = b * (64 * CSTRIDE) + d * (Hh * Ww) + h * Ww;
    const float* xblk = x + base0;

    // ---- stage X^T bf16 into swizzled LDS: 768 16B-chunks, 2 per thread ----
#pragma unroll
    for (int k = 0; k < 2; ++k) {
        int idx = t + k * BDIM;          // 0..767
        int w  = idx % Ww;
        int c8 = idx / Ww;               // chunk 0..7 (c = c8*8 .. +8)
        bf16x8 pk;
#pragma unroll
        for (int j = 0; j < 8; ++j)
            pk[j] = (bf16_t)xblk[(c8 * 8 + j) * CSTRIDE + w];
        *(bf16x8*)(&Xs[w * 64 + ((c8 ^ (w & 7)) << 3)]) = pk;
    }

    // ---- per-lane weight fragments + bias/PE scalars (global, L1-hot) ----
    bf16x8 wq[2][2], wk[2][2], wv[4][2];
#pragma unroll
    for (int mt = 0; mt < 2; ++mt)
#pragma unroll
        for (int kt = 0; kt < 2; ++kt) {
            wq[mt][kt] = ldw(Wq, mt * 16 + l16, kt * 32 + quad * 8);
            wk[mt][kt] = ldw(Wk, mt * 16 + l16, kt * 32 + quad * 8);
        }
#pragma unroll
    for (int ct = 0; ct < 4; ++ct)
#pragma unroll
        for (int kt = 0; kt < 2; ++kt)
            wv[ct][kt] = ldw(Wv, ct * 16 + l16, kt * 32 + quad * 8);

    float bqv[2][4], bkv[2][4], fqk[2][2];
#pragma unroll
    for (int mt = 0; mt < 2; ++mt) {
#pragma unroll
        for (int r = 0; r < 4; ++r) {
            bqv[mt][r] = bq[mt * 16 + quad * 4 + r];
            bkv[mt][r] = bk[mt * 16 + quad * 4 + r];
        }
#pragma unroll
        for (int p = 0; p < 2; ++p)
            fqk[mt][p] = __expf(-(float)(mt * 16 + quad * 4 + 2 * p) * FREQ_QK);
    }
    float bvv[4], fv[4], sdv[4], cdv[4];
#pragma unroll
    for (int ct = 0; ct < 4; ++ct) {
        int cv = ct * 16 + l16;
        bvv[ct] = bv[cv];
        fv[ct]  = __expf(-(float)(cv & ~1) * FREQ_V);
        __sincosf(fv[ct], &sdv[ct], &cdv[ct]);   // rotation step for j -> j+1
    }
    const float g = gamma[0];
    const bool oddc = (l16 & 1);

    __syncthreads();   // the ONLY barrier: Xs visible to all waves

    const int iw = wid * 16 + l16;   // this wave's i position for this lane

    // ---- Q-tile: D[m=q][n=i] -> A-fragments for S, entirely in registers ----
    bf16x8 xfi0 = *(const bf16x8*)(&Xs[iw * 64 + (((0 + quad) ^ (iw & 7)) << 3)]);
    bf16x8 xfi1 = *(const bf16x8*)(&Xs[iw * 64 + (((4 + quad) ^ (iw & 7)) << 3)]);
    bf16x4 aq[2];
#pragma unroll
    for (int mt = 0; mt < 2; ++mt) {
        floatx4 dq = {0.f, 0.f, 0.f, 0.f};
        dq = mfma32(wq[mt][0], xfi0, dq);
        dq = mfma32(wq[mt][1], xfi1, dq);
        bf16x4 a;
#pragma unroll
        for (int p = 0; p < 2; ++p) {
            float sn, cs;
            __sincosf((float)iw * fqk[mt][p], &sn, &cs);
            a[2 * p]     = (bf16_t)(dq[2 * p]     + bqv[mt][2 * p]     + sn);
            a[2 * p + 1] = (bf16_t)(dq[2 * p + 1] + bqv[mt][2 * p + 1] + cs);
        }
        aq[mt] = a;
    }

    // ---- K-tiles (redundant per wave) + S, register-to-register ----
    floatx4 sacc[6];
#pragma unroll
    for (int jt = 0; jt < 6; ++jt) {
        int jw = jt * 16 + l16;
        bf16x8 xfj0 = *(const bf16x8*)(&Xs[jw * 64 + (((0 + quad) ^ (jw & 7)) << 3)]);
        bf16x8 xfj1 = *(const bf16x8*)(&Xs[jw * 64 + (((4 + quad) ^ (jw & 7)) << 3)]);
        floatx4 s = {0.f, 0.f, 0.f, 0.f};
#pragma unroll
        for (int mt = 0; mt < 2; ++mt) {
            floatx4 dk = {0.f, 0.f, 0.f, 0.f};
            dk = mfma32(wk[mt][0], xfj0, dk);
            dk = mfma32(wk[mt][1], xfj1, dk);
            bf16x4 bk4;
#pragma unroll
            for (int p = 0; p < 2; ++p) {
                float sn, cs;
                __sincosf((float)jw * fqk[mt][p], &sn, &cs);
                bk4[2 * p]     = (bf16_t)(dk[2 * p]     + bkv[mt][2 * p]     + sn);
                bk4[2 * p + 1] = (bf16_t)(dk[2 * p + 1] + bkv[mt][2 * p + 1] + cs);
            }
            s = mfma32(pad_hi(aq[mt]), pad_hi(bk4), s);   // k=16 via zero-pad
        }
        sacc[jt] = s;
    }

    // ---- softmax in registers (row i = quad*4+r across 16 lanes x 6 regs) ----
#pragma unroll
    for (int r = 0; r < 4; ++r) {
        float m = sacc[0][r];
#pragma unroll
        for (int jt = 1; jt < 6; ++jt) m = fmaxf(m, sacc[jt][r]);
#pragma unroll
        for (int msk = 1; msk < 16; msk <<= 1) m = fmaxf(m, __shfl_xor(m, msk));
        float e[6], sum = 0.f;
#pragma unroll
        for (int jt = 0; jt < 6; ++jt) { e[jt] = __expf(sacc[jt][r] - m); sum += e[jt]; }
#pragma unroll
        for (int msk = 1; msk < 16; msk <<= 1) sum += __shfl_xor(sum, msk);
        float inv = 1.0f / sum;
#pragma unroll
        for (int jt = 0; jt < 6; ++jt)
            Psw[(quad * 4 + r) * PS_STRIDE + jt * 16 + l16] = (bf16_t)(e[jt] * inv);
    }

    // ---- V-tiles (redundant per wave) + PV, P via wave-private LDS ----
    floatx4 oacc[4];
#pragma unroll
    for (int ct = 0; ct < 4; ++ct) oacc[ct] = floatx4{0.f, 0.f, 0.f, 0.f};

#pragma unroll
    for (int jt = 0; jt < 6; ++jt) {
        int jw = jt * 16 + l16;
        bf16x8 xfj0 = *(const bf16x8*)(&Xs[jw * 64 + (((0 + quad) ^ (jw & 7)) << 3)]);
        bf16x8 xfj1 = *(const bf16x8*)(&Xs[jw * 64 + (((4 + quad) ^ (jw & 7)) << 3)]);
        // P B-frag: lane n=i=l16, true k = j = jt*16 + quad*4 + r
        bf16x4 p4 = *(const bf16x4*)(&Psw[l16 * PS_STRIDE + jt * 16 + quad * 4]);
        bf16x8 pb = pad_hi(p4);
#pragma unroll
        for (int ct = 0; ct < 4; ++ct) {
            floatx4 dv = {0.f, 0.f, 0.f, 0.f};   // D[m=j][n=c]
            dv = mfma32(xfj0, wv[ct][0], dv);
            dv = mfma32(xfj1, wv[ct][1], dv);
            // pe_v[c][j]: freq per lane (c), angle stepped by rotation over r
            float s0, c0;
            __sincosf(fv[ct] * (float)(jt * 16 + quad * 4), &s0, &c0);
            bf16x4 av;
#pragma unroll
            for (int r = 0; r < 4; ++r) {
                float pe = oddc ? c0 : s0;
                av[r] = (bf16_t)(dv[r] + bvv[ct] + pe);
                float ns = s0 * cdv[ct] + c0 * sdv[ct];
                float nc = c0 * cdv[ct] - s0 * sdv[ct];
                s0 = ns; c0 = nc;
            }
            oacc[ct] = mfma32(pad_hi(av), pb, oacc[ct]);  // k=16 via zero-pad
        }
    }

    // ---- epilogue: y = gamma*o + x (x residual from bf16 Xs; no global re-read) ----
#pragma unroll
    for (int ct = 0; ct < 4; ++ct) {
#pragma unroll
        for (int r = 0; r < 4; ++r) {
            int c  = ct * 16 + quad * 4 + r;
            float xr = (float)Xs[iw * 64 + ((((c >> 3) ^ (iw & 7)) << 3)) + (c & 7)];
            int gi = base0 + c * CSTRIDE + wid * 16 + l16;
            y[gi] = fmaf(g, oacc[ct][r], xr);
        }
    }
}

extern "C" void kernel_launch(void* const* d_in, const int* in_sizes, int n_in,
                              void* d_out, int out_size, void* d_ws, size_t ws_size,
                              hipStream_t stream) {
    const float* x     = (const float*)d_in[0];
    const float* Wq    = (const float*)d_in[1];
    const float* bq    = (const float*)d_in[2];
    const float* Wk    = (const float*)d_in[3];
    const float* bk    = (const float*)d_in[4];
    const float* Wv    = (const float*)d_in[5];
    const float* bv    = (const float*)d_in[6];
    const float* gamma = (const float*)d_in[7];
    float* y = (float*)d_out;

    dim3 grid(2 * Dd * Hh);   // one block per (b,d,h)
    row_attn_v4<<<grid, BDIM, 0, stream>>>(x, Wq, bq, Wk, bk, Wv, bv, gamma, y);
}